// Round 1
// baseline (946.903 us; speedup 1.0000x reference)
//
#include <hip/hip_runtime.h>

#define NEG_SLOPE 0.2f

// ---------------- CSR build (once per call, reused by all 3 layers) ----------

__global__ void init_hist(int* __restrict__ hist, int n) {
    int i = blockIdx.x * blockDim.x + threadIdx.x;
    if (i < n) hist[i] = 1;  // self-loop contributes 1 incoming edge per node
}

__global__ void edge_hist(const int* __restrict__ ei, int* __restrict__ hist, int E) {
    int e = blockIdx.x * blockDim.x + threadIdx.x;
    if (e < E) atomicAdd(&hist[ei[E + e]], 1);  // dst row of edge_index
}

// single-block exclusive scan over n counts -> rowptr[0..n], also seeds fill[]
__global__ __launch_bounds__(1024) void scan_kernel(const int* __restrict__ hist,
                                                    int* __restrict__ rowptr,
                                                    int* __restrict__ fill, int n) {
    __shared__ int wsum[16];
    __shared__ int carry_s;
    int tid = threadIdx.x;
    int lane = tid & 63, wid = tid >> 6;
    if (tid == 0) carry_s = 0;
    __syncthreads();
    for (int start = 0; start < n; start += 1024) {
        int i = start + tid;
        int v = (i < n) ? hist[i] : 0;
        int sv = v;
        #pragma unroll
        for (int d = 1; d < 64; d <<= 1) {
            int t = __shfl_up(sv, d);
            if (lane >= d) sv += t;
        }
        if (lane == 63) wsum[wid] = sv;
        __syncthreads();
        if (tid < 16) {
            int ws = wsum[tid];
            #pragma unroll
            for (int d = 1; d < 16; d <<= 1) {
                int t = __shfl_up(ws, d);
                if (tid >= d) ws += t;
            }
            wsum[tid] = ws;
        }
        __syncthreads();
        int base = carry_s;
        int waveoff = wid ? wsum[wid - 1] : 0;
        int excl = base + waveoff + sv - v;
        if (i < n) { rowptr[i] = excl; fill[i] = excl; }
        int tot = wsum[15];
        __syncthreads();
        if (tid == 0) carry_s = base + tot;
        __syncthreads();
    }
    if (tid == 0) rowptr[n] = carry_s;
}

__global__ void scatter_kernel(const int* __restrict__ ei, int* __restrict__ fill,
                               int* __restrict__ col, int E, int n) {
    int i = blockIdx.x * blockDim.x + threadIdx.x;
    if (i >= E + n) return;
    int s, d;
    if (i < E) { s = ei[i]; d = ei[E + i]; }
    else       { s = d = i - E; }            // self-loops
    int pos = atomicAdd(&fill[d], 1);
    col[pos] = s;
}

// ---------------- per-layer kernels ----------------

// h = x @ W   (x: [n,K], W: [K,HC], h: [n,HC]); one thread per output element.
__global__ void gemm_kernel(const float* __restrict__ x, const float* __restrict__ W,
                            float* __restrict__ h, int n, int K, int HC) {
    int idx = blockIdx.x * blockDim.x + threadIdx.x;
    if (idx >= n * HC) return;
    int row = idx / HC, j = idx - (idx / HC) * HC;
    const float* xr = x + (size_t)row * K;
    float acc = 0.f;
    for (int k = 0; k < K; k += 4) {
        float4 xv = *(const float4*)(xr + k);
        acc = fmaf(xv.x, W[(k + 0) * HC + j], acc);
        acc = fmaf(xv.y, W[(k + 1) * HC + j], acc);
        acc = fmaf(xv.z, W[(k + 2) * HC + j], acc);
        acc = fmaf(xv.w, W[(k + 3) * HC + j], acc);
    }
    h[idx] = acc;
}

// as[n,h] = sum_c h[n,h,c]*a_src[h,c]  (and same for ad); one thread per (n,h)
__global__ void alpha_kernel(const float* __restrict__ h, const float* __restrict__ a_src,
                             const float* __restrict__ a_dst, float* __restrict__ as_,
                             float* __restrict__ ad_, int n, int H, int C) {
    int idx = blockIdx.x * blockDim.x + threadIdx.x;
    if (idx >= n * H) return;
    int hh = idx % H;
    const float* hr = h + (size_t)(idx / H) * H * C + hh * C;
    float s = 0.f, d = 0.f;
    for (int c = 0; c < C; ++c) {
        float v = hr[c];
        s = fmaf(v, a_src[hh * C + c], s);
        d = fmaf(v, a_dst[hh * C + c], d);
    }
    as_[idx] = s;
    ad_[idx] = d;
}

// One wave per destination node: softmax over incoming edges + weighted gather.
// lane -> output channel (hh = lane/C, c = lane%C). Two passes: max, then
// fused exp-sum + weighted accumulate; divide once at the end.
template <int H, int C, bool RELU>
__global__ void aggr_kernel(const float* __restrict__ h, const float* __restrict__ as_,
                            const float* __restrict__ ad_, const int* __restrict__ rowptr,
                            const int* __restrict__ col, const float* __restrict__ b,
                            float* __restrict__ out, int n) {
    constexpr int HC = H * C;
    int wid = (int)(((size_t)blockIdx.x * blockDim.x + threadIdx.x) >> 6);
    int lane = threadIdx.x & 63;
    if (wid >= n) return;
    int hh = (lane < HC) ? (lane / C) : 0;
    float adi = ad_[wid * H + hh];
    int p0 = rowptr[wid], p1 = rowptr[wid + 1];

    float m = -3.4e38f;
    for (int p = p0; p < p1; ++p) {
        int s = col[p];
        float e = as_[s * H + hh] + adi;
        e = (e >= 0.f) ? e : NEG_SLOPE * e;   // leaky_relu
        m = fmaxf(m, e);
    }
    float sum = 0.f, acc = 0.f;
    for (int p = p0; p < p1; ++p) {
        int s = col[p];
        float e = as_[s * H + hh] + adi;
        e = (e >= 0.f) ? e : NEG_SLOPE * e;
        float w = expf(e - m);
        sum += w;
        if (lane < HC) acc = fmaf(w, h[(size_t)s * HC + lane], acc);
    }
    if (lane < HC) {
        float r = acc / (sum + 1e-16f) + b[lane];
        out[(size_t)wid * HC + lane] = RELU ? fmaxf(r, 0.f) : r;
    }
}

// ---------------- launch ----------------

extern "C" void kernel_launch(void* const* d_in, const int* in_sizes, int n_in,
                              void* d_out, int out_size, void* d_ws, size_t ws_size,
                              hipStream_t stream) {
    const float* x      = (const float*)d_in[0];
    const int*   ei     = (const int*)d_in[1];
    const float* W1     = (const float*)d_in[2];
    const float* a_src1 = (const float*)d_in[3];
    const float* a_dst1 = (const float*)d_in[4];
    const float* b1     = (const float*)d_in[5];
    const float* W2     = (const float*)d_in[6];
    const float* a_src2 = (const float*)d_in[7];
    const float* a_dst2 = (const float*)d_in[8];
    const float* b2     = (const float*)d_in[9];
    const float* W3     = (const float*)d_in[10];
    const float* a_src3 = (const float*)d_in[11];
    const float* a_dst3 = (const float*)d_in[12];
    const float* b3     = (const float*)d_in[13];
    float* out = (float*)d_out;

    const int NFEAT = 256, NHID = 64;
    const int N = in_sizes[0] / NFEAT;   // 50000
    const int E = in_sizes[1] / 2;       // 800000
    const int M = E + N;                 // edges incl. self-loops

    char* p = (char*)d_ws;
    auto alloc = [&](size_t bytes) {
        char* r = p;
        p += (bytes + 255) & ~(size_t)255;
        return r;
    };
    int*   hist   = (int*)alloc((size_t)N * 4);
    int*   rowptr = (int*)alloc((size_t)(N + 1) * 4);
    int*   fill   = (int*)alloc((size_t)N * 4);
    int*   col    = (int*)alloc((size_t)M * 4);
    float* hbuf   = (float*)alloc((size_t)N * NHID * 4);
    float* xbuf   = (float*)alloc((size_t)N * NHID * 4);
    float* asb    = (float*)alloc((size_t)N * 4 * 4);
    float* adb    = (float*)alloc((size_t)N * 4 * 4);

    dim3 blk(256);

    // CSR build (shared across all layers)
    init_hist<<<(N + 255) / 256, blk, 0, stream>>>(hist, N);
    edge_hist<<<(E + 255) / 256, blk, 0, stream>>>(ei, hist, E);
    scan_kernel<<<1, 1024, 0, stream>>>(hist, rowptr, fill, N);
    scatter_kernel<<<(M + 255) / 256, blk, 0, stream>>>(ei, fill, col, E, N);

    // layer 1: 256 -> 4x16, relu
    gemm_kernel<<<((size_t)N * 64 + 255) / 256, blk, 0, stream>>>(x, W1, hbuf, N, 256, 64);
    alpha_kernel<<<(N * 4 + 255) / 256, blk, 0, stream>>>(hbuf, a_src1, a_dst1, asb, adb, N, 4, 16);
    aggr_kernel<4, 16, true><<<((size_t)N * 64 + 255) / 256, blk, 0, stream>>>(
        hbuf, asb, adb, rowptr, col, b1, xbuf, N);

    // layer 2: 64 -> 4x16, relu
    gemm_kernel<<<((size_t)N * 64 + 255) / 256, blk, 0, stream>>>(xbuf, W2, hbuf, N, 64, 64);
    alpha_kernel<<<(N * 4 + 255) / 256, blk, 0, stream>>>(hbuf, a_src2, a_dst2, asb, adb, N, 4, 16);
    aggr_kernel<4, 16, true><<<((size_t)N * 64 + 255) / 256, blk, 0, stream>>>(
        hbuf, asb, adb, rowptr, col, b2, xbuf, N);

    // layer 3: 64 -> 1x40, no relu
    gemm_kernel<<<((size_t)N * 40 + 255) / 256, blk, 0, stream>>>(xbuf, W3, hbuf, N, 64, 40);
    alpha_kernel<<<(N + 255) / 256, blk, 0, stream>>>(hbuf, a_src3, a_dst3, asb, adb, N, 1, 40);
    aggr_kernel<1, 40, false><<<((size_t)N * 64 + 255) / 256, blk, 0, stream>>>(
        hbuf, asb, adb, rowptr, col, b3, out, N);
}

// Round 2
// 748.986 us; speedup vs baseline: 1.2642x; 1.2642x over previous
//
#include <hip/hip_runtime.h>

#define NEG_SLOPE 0.2f

// ---------------- CSR build (once per call, reused by all 3 layers) ----------

__global__ void init_hist(int* __restrict__ hist, int n) {
    int i = blockIdx.x * blockDim.x + threadIdx.x;
    if (i < n) hist[i] = 1;  // self-loop contributes 1 incoming edge per node
}

__global__ void edge_hist(const int* __restrict__ ei, int* __restrict__ hist, int E) {
    int e = blockIdx.x * blockDim.x + threadIdx.x;
    if (e < E) atomicAdd(&hist[ei[E + e]], 1);  // dst row of edge_index
}

// single-block exclusive scan over n counts -> rowptr[0..n], also seeds fill[]
__global__ __launch_bounds__(1024) void scan_kernel(const int* __restrict__ hist,
                                                    int* __restrict__ rowptr,
                                                    int* __restrict__ fill, int n) {
    __shared__ int wsum[16];
    __shared__ int carry_s;
    int tid = threadIdx.x;
    int lane = tid & 63, wid = tid >> 6;
    if (tid == 0) carry_s = 0;
    __syncthreads();
    for (int start = 0; start < n; start += 1024) {
        int i = start + tid;
        int v = (i < n) ? hist[i] : 0;
        int sv = v;
        #pragma unroll
        for (int d = 1; d < 64; d <<= 1) {
            int t = __shfl_up(sv, d);
            if (lane >= d) sv += t;
        }
        if (lane == 63) wsum[wid] = sv;
        __syncthreads();
        if (tid < 16) {
            int ws = wsum[tid];
            #pragma unroll
            for (int d = 1; d < 16; d <<= 1) {
                int t = __shfl_up(ws, d);
                if (tid >= d) ws += t;
            }
            wsum[tid] = ws;
        }
        __syncthreads();
        int base = carry_s;
        int waveoff = wid ? wsum[wid - 1] : 0;
        int excl = base + waveoff + sv - v;
        if (i < n) { rowptr[i] = excl; fill[i] = excl; }
        int tot = wsum[15];
        __syncthreads();
        if (tid == 0) carry_s = base + tot;
        __syncthreads();
    }
    if (tid == 0) rowptr[n] = carry_s;
}

__global__ void scatter_kernel(const int* __restrict__ ei, int* __restrict__ fill,
                               int* __restrict__ col, int E, int n) {
    int i = blockIdx.x * blockDim.x + threadIdx.x;
    if (i >= E + n) return;
    int s, d;
    if (i < E) { s = ei[i]; d = ei[E + i]; }
    else       { s = d = i - E; }            // self-loops
    int pos = atomicAdd(&fill[d], 1);
    col[pos] = s;
}

// ---------------- tiled GEMM (+ optional fused alpha for H=4,C=16 layers) ----

// h = x @ W. Block: 256 threads -> 64-row x HC-col tile, 4x4 register tile
// per thread. LDS: xs[64][68] (pad 4 keeps 16B-aligned float4 rows, breaks
// bank stride) + ws[64][64] = 33.8 KB -> 4 blocks/CU.
// FUSE_ALPHA: also emits as_[n][4], ad_[n][4] via 4-lane shfl reduction.
template <int K, int HC, bool FUSE_ALPHA>
__global__ __launch_bounds__(256) void gemm_tiled(
    const float* __restrict__ x, const float* __restrict__ W,
    const float* __restrict__ a_src, const float* __restrict__ a_dst,
    float* __restrict__ h, float* __restrict__ as_, float* __restrict__ ad_,
    int n) {
    __shared__ float xs[64][68];
    __shared__ float ws[64][64];
    const int t = threadIdx.x;
    const int tx = t & 15;        // col group: cols tx*4 .. tx*4+3
    const int ty = t >> 4;        // row group: rows ty*4 .. ty*4+3
    const int rowBase = blockIdx.x * 64;

    float acc[4][4];
    #pragma unroll
    for (int r = 0; r < 4; ++r)
        #pragma unroll
        for (int c = 0; c < 4; ++c) acc[r][c] = 0.f;

    const int sr = t >> 2;        // staging row (0..63)
    const int sq = t & 3;         // staging quarter

    for (int kb = 0; kb < K; kb += 64) {
        __syncthreads();
        // stage x[rowBase..+63][kb..kb+63] -> xs
        {
            int g = rowBase + sr;
            const float* xr = x + (size_t)g * K + kb;
            #pragma unroll
            for (int i = 0; i < 4; ++i) {
                int ko = sq * 16 + i * 4;
                float4 v = make_float4(0.f, 0.f, 0.f, 0.f);
                if (g < n) v = *(const float4*)(xr + ko);
                *(float4*)&xs[sr][ko] = v;
            }
        }
        // stage W[kb..kb+63][0..HC) -> ws (zero-pad cols to 64)
        if (HC == 64) {
            #pragma unroll
            for (int i = 0; i < 4; ++i) {
                int li = t + i * 256;          // float4 index 0..1023
                int k = li >> 4, j4 = (li & 15) * 4;
                *(float4*)&ws[k][j4] = *(const float4*)&W[(size_t)(kb + k) * 64 + j4];
            }
        } else {
            for (int i = t; i < 64 * 64; i += 256) {
                int k = i >> 6, j = i & 63;
                ws[k][j] = (j < HC) ? W[(size_t)(kb + k) * HC + j] : 0.f;
            }
        }
        __syncthreads();

        #pragma unroll
        for (int k = 0; k < 64; k += 4) {
            float xr[4][4];
            #pragma unroll
            for (int r = 0; r < 4; ++r) {
                float4 v = *(const float4*)&xs[ty * 4 + r][k];
                xr[r][0] = v.x; xr[r][1] = v.y; xr[r][2] = v.z; xr[r][3] = v.w;
            }
            float wr[4][4];
            #pragma unroll
            for (int kk = 0; kk < 4; ++kk) {
                float4 v = *(const float4*)&ws[k + kk][tx * 4];
                wr[kk][0] = v.x; wr[kk][1] = v.y; wr[kk][2] = v.z; wr[kk][3] = v.w;
            }
            #pragma unroll
            for (int kk = 0; kk < 4; ++kk)
                #pragma unroll
                for (int r = 0; r < 4; ++r)
                    #pragma unroll
                    for (int c = 0; c < 4; ++c)
                        acc[r][c] = fmaf(xr[r][kk], wr[kk][c], acc[r][c]);
        }
    }

    // epilogue
    if (FUSE_ALPHA) {
        // H=4, C=16: head hh = tx>>2, channel base (tx&3)*4
        const int hh = tx >> 2;
        const int cb = (tx & 3) * 4;
        float asv[4], adv[4];
        #pragma unroll
        for (int c = 0; c < 4; ++c) {
            asv[c] = a_src[hh * 16 + cb + c];
            adv[c] = a_dst[hh * 16 + cb + c];
        }
        #pragma unroll
        for (int r = 0; r < 4; ++r) {
            float ps = 0.f, pd = 0.f;
            #pragma unroll
            for (int c = 0; c < 4; ++c) {
                ps = fmaf(acc[r][c], asv[c], ps);
                pd = fmaf(acc[r][c], adv[c], pd);
            }
            ps += __shfl_xor(ps, 1); ps += __shfl_xor(ps, 2);
            pd += __shfl_xor(pd, 1); pd += __shfl_xor(pd, 2);
            int g = rowBase + ty * 4 + r;
            if (g < n) {
                float4 v = make_float4(acc[r][0], acc[r][1], acc[r][2], acc[r][3]);
                *(float4*)&h[(size_t)g * 64 + tx * 4] = v;
                if ((tx & 3) == 0) {
                    as_[g * 4 + hh] = ps;
                    ad_[g * 4 + hh] = pd;
                }
            }
        }
    } else {
        #pragma unroll
        for (int r = 0; r < 4; ++r) {
            int g = rowBase + ty * 4 + r;
            if (g < n && tx * 4 < HC) {   // HC=40: tx<10 fully valid (40%4==0)
                float4 v = make_float4(acc[r][0], acc[r][1], acc[r][2], acc[r][3]);
                *(float4*)&h[(size_t)g * HC + tx * 4] = v;
            }
        }
    }
}

// as[n,h] = sum_c h[n,h,c]*a_src[h,c]; one thread per (n,h) — layer 3 only
__global__ void alpha_kernel(const float* __restrict__ h, const float* __restrict__ a_src,
                             const float* __restrict__ a_dst, float* __restrict__ as_,
                             float* __restrict__ ad_, int n, int H, int C) {
    int idx = blockIdx.x * blockDim.x + threadIdx.x;
    if (idx >= n * H) return;
    int hh = idx % H;
    const float* hr = h + (size_t)(idx / H) * H * C + hh * C;
    float s = 0.f, d = 0.f;
    for (int c = 0; c < C; ++c) {
        float v = hr[c];
        s = fmaf(v, a_src[hh * C + c], s);
        d = fmaf(v, a_dst[hh * C + c], d);
    }
    as_[idx] = s;
    ad_[idx] = d;
}

// One wave per destination node: softmax over incoming edges + weighted gather.
template <int H, int C, bool RELU>
__global__ void aggr_kernel(const float* __restrict__ h, const float* __restrict__ as_,
                            const float* __restrict__ ad_, const int* __restrict__ rowptr,
                            const int* __restrict__ col, const float* __restrict__ b,
                            float* __restrict__ out, int n) {
    constexpr int HC = H * C;
    int wid = (int)(((size_t)blockIdx.x * blockDim.x + threadIdx.x) >> 6);
    int lane = threadIdx.x & 63;
    if (wid >= n) return;
    int hh = (lane < HC) ? (lane / C) : 0;
    float adi = ad_[wid * H + hh];
    int p0 = rowptr[wid], p1 = rowptr[wid + 1];

    float m = -3.4e38f;
    for (int p = p0; p < p1; ++p) {
        int s = col[p];
        float e = as_[s * H + hh] + adi;
        e = (e >= 0.f) ? e : NEG_SLOPE * e;   // leaky_relu
        m = fmaxf(m, e);
    }
    float sum = 0.f, acc = 0.f;
    for (int p = p0; p < p1; ++p) {
        int s = col[p];
        float e = as_[s * H + hh] + adi;
        e = (e >= 0.f) ? e : NEG_SLOPE * e;
        float w = expf(e - m);
        sum += w;
        if (lane < HC) acc = fmaf(w, h[(size_t)s * HC + lane], acc);
    }
    if (lane < HC) {
        float r = acc / (sum + 1e-16f) + b[lane];
        out[(size_t)wid * HC + lane] = RELU ? fmaxf(r, 0.f) : r;
    }
}

// ---------------- launch ----------------

extern "C" void kernel_launch(void* const* d_in, const int* in_sizes, int n_in,
                              void* d_out, int out_size, void* d_ws, size_t ws_size,
                              hipStream_t stream) {
    const float* x      = (const float*)d_in[0];
    const int*   ei     = (const int*)d_in[1];
    const float* W1     = (const float*)d_in[2];
    const float* a_src1 = (const float*)d_in[3];
    const float* a_dst1 = (const float*)d_in[4];
    const float* b1     = (const float*)d_in[5];
    const float* W2     = (const float*)d_in[6];
    const float* a_src2 = (const float*)d_in[7];
    const float* a_dst2 = (const float*)d_in[8];
    const float* b2     = (const float*)d_in[9];
    const float* W3     = (const float*)d_in[10];
    const float* a_src3 = (const float*)d_in[11];
    const float* a_dst3 = (const float*)d_in[12];
    const float* b3     = (const float*)d_in[13];
    float* out = (float*)d_out;

    const int NFEAT = 256, NHID = 64;
    const int N = in_sizes[0] / NFEAT;   // 50000
    const int E = in_sizes[1] / 2;       // 800000
    const int M = E + N;                 // edges incl. self-loops

    char* p = (char*)d_ws;
    auto alloc = [&](size_t bytes) {
        char* r = p;
        p += (bytes + 255) & ~(size_t)255;
        return r;
    };
    int*   hist   = (int*)alloc((size_t)N * 4);
    int*   rowptr = (int*)alloc((size_t)(N + 1) * 4);
    int*   fill   = (int*)alloc((size_t)N * 4);
    int*   col    = (int*)alloc((size_t)M * 4);
    float* hbuf   = (float*)alloc((size_t)N * NHID * 4);
    float* xbuf   = (float*)alloc((size_t)N * NHID * 4);
    float* asb    = (float*)alloc((size_t)N * 4 * 4);
    float* adb    = (float*)alloc((size_t)N * 4 * 4);

    dim3 blk(256);
    const int gemmGrid = (N + 63) / 64;

    // CSR build (shared across all layers)
    init_hist<<<(N + 255) / 256, blk, 0, stream>>>(hist, N);
    edge_hist<<<(E + 255) / 256, blk, 0, stream>>>(ei, hist, E);
    scan_kernel<<<1, 1024, 0, stream>>>(hist, rowptr, fill, N);
    scatter_kernel<<<(M + 255) / 256, blk, 0, stream>>>(ei, fill, col, E, N);

    // layer 1: 256 -> 4x16, relu  (alpha fused into gemm)
    gemm_tiled<256, 64, true><<<gemmGrid, blk, 0, stream>>>(
        x, W1, a_src1, a_dst1, hbuf, asb, adb, N);
    aggr_kernel<4, 16, true><<<((size_t)N * 64 + 255) / 256, blk, 0, stream>>>(
        hbuf, asb, adb, rowptr, col, b1, xbuf, N);

    // layer 2: 64 -> 4x16, relu
    gemm_tiled<64, 64, true><<<gemmGrid, blk, 0, stream>>>(
        xbuf, W2, a_src2, a_dst2, hbuf, asb, adb, N);
    aggr_kernel<4, 16, true><<<((size_t)N * 64 + 255) / 256, blk, 0, stream>>>(
        hbuf, asb, adb, rowptr, col, b2, xbuf, N);

    // layer 3: 64 -> 1x40, no relu
    gemm_tiled<64, 40, false><<<gemmGrid, blk, 0, stream>>>(
        xbuf, W3, nullptr, nullptr, hbuf, nullptr, nullptr, N);
    alpha_kernel<<<(N + 255) / 256, blk, 0, stream>>>(hbuf, a_src3, a_dst3, asb, adb, N, 1, 40);
    aggr_kernel<1, 40, false><<<((size_t)N * 64 + 255) / 256, blk, 0, stream>>>(
        hbuf, asb, adb, rowptr, col, b3, out, N);
}

// Round 3
// 455.293 us; speedup vs baseline: 2.0798x; 1.6451x over previous
//
#include <hip/hip_runtime.h>

#define NEG_SLOPE 0.2f

// ---------------- CSR build (once per call, reused by all 3 layers) ----------

__global__ void init_hist(int* __restrict__ hist, int n) {
    int i = blockIdx.x * blockDim.x + threadIdx.x;
    if (i < n) hist[i] = 1;  // self-loop contributes 1 incoming edge per node
}

__global__ void edge_hist(const int* __restrict__ ei, int* __restrict__ hist, int E) {
    int e = blockIdx.x * blockDim.x + threadIdx.x;
    if (e < E) atomicAdd(&hist[ei[E + e]], 1);  // dst row of edge_index
}

// single-block exclusive scan over n counts -> rowptr[0..n], also seeds fill[]
__global__ __launch_bounds__(1024) void scan_kernel(const int* __restrict__ hist,
                                                    int* __restrict__ rowptr,
                                                    int* __restrict__ fill, int n) {
    __shared__ int wsum[16];
    __shared__ int carry_s;
    int tid = threadIdx.x;
    int lane = tid & 63, wid = tid >> 6;
    if (tid == 0) carry_s = 0;
    __syncthreads();
    for (int start = 0; start < n; start += 1024) {
        int i = start + tid;
        int v = (i < n) ? hist[i] : 0;
        int sv = v;
        #pragma unroll
        for (int d = 1; d < 64; d <<= 1) {
            int t = __shfl_up(sv, d);
            if (lane >= d) sv += t;
        }
        if (lane == 63) wsum[wid] = sv;
        __syncthreads();
        if (tid < 16) {
            int ws = wsum[tid];
            #pragma unroll
            for (int d = 1; d < 16; d <<= 1) {
                int t = __shfl_up(ws, d);
                if (tid >= d) ws += t;
            }
            wsum[tid] = ws;
        }
        __syncthreads();
        int base = carry_s;
        int waveoff = wid ? wsum[wid - 1] : 0;
        int excl = base + waveoff + sv - v;
        if (i < n) { rowptr[i] = excl; fill[i] = excl; }
        int tot = wsum[15];
        __syncthreads();
        if (tid == 0) carry_s = base + tot;
        __syncthreads();
    }
    if (tid == 0) rowptr[n] = carry_s;
}

__global__ void scatter_kernel(const int* __restrict__ ei, int* __restrict__ fill,
                               int* __restrict__ col, int E, int n) {
    int i = blockIdx.x * blockDim.x + threadIdx.x;
    if (i >= E + n) return;
    int s, d;
    if (i < E) { s = ei[i]; d = ei[E + i]; }
    else       { s = d = i - E; }            // self-loops
    int pos = atomicAdd(&fill[d], 1);
    col[pos] = s;
}

// ---------------- tiled GEMM (+ optional fused alpha for H=4,C=16 layers) ----

template <int K, int HC, bool FUSE_ALPHA>
__global__ __launch_bounds__(256) void gemm_tiled(
    const float* __restrict__ x, const float* __restrict__ W,
    const float* __restrict__ a_src, const float* __restrict__ a_dst,
    float* __restrict__ h, float* __restrict__ as_, float* __restrict__ ad_,
    int n) {
    __shared__ float xs[64][68];
    __shared__ float ws[64][64];
    const int t = threadIdx.x;
    const int tx = t & 15;        // col group: cols tx*4 .. tx*4+3
    const int ty = t >> 4;        // row group: rows ty*4 .. ty*4+3
    const int rowBase = blockIdx.x * 64;

    float acc[4][4];
    #pragma unroll
    for (int r = 0; r < 4; ++r)
        #pragma unroll
        for (int c = 0; c < 4; ++c) acc[r][c] = 0.f;

    const int sr = t >> 2;        // staging row (0..63)
    const int sq = t & 3;         // staging quarter

    for (int kb = 0; kb < K; kb += 64) {
        __syncthreads();
        {
            int g = rowBase + sr;
            const float* xr = x + (size_t)g * K + kb;
            #pragma unroll
            for (int i = 0; i < 4; ++i) {
                int ko = sq * 16 + i * 4;
                float4 v = make_float4(0.f, 0.f, 0.f, 0.f);
                if (g < n) v = *(const float4*)(xr + ko);
                *(float4*)&xs[sr][ko] = v;
            }
        }
        if (HC == 64) {
            #pragma unroll
            for (int i = 0; i < 4; ++i) {
                int li = t + i * 256;          // float4 index 0..1023
                int k = li >> 4, j4 = (li & 15) * 4;
                *(float4*)&ws[k][j4] = *(const float4*)&W[(size_t)(kb + k) * 64 + j4];
            }
        } else {
            for (int i = t; i < 64 * 64; i += 256) {
                int k = i >> 6, j = i & 63;
                ws[k][j] = (j < HC) ? W[(size_t)(kb + k) * HC + j] : 0.f;
            }
        }
        __syncthreads();

        #pragma unroll
        for (int k = 0; k < 64; k += 4) {
            float xr[4][4];
            #pragma unroll
            for (int r = 0; r < 4; ++r) {
                float4 v = *(const float4*)&xs[ty * 4 + r][k];
                xr[r][0] = v.x; xr[r][1] = v.y; xr[r][2] = v.z; xr[r][3] = v.w;
            }
            float wr[4][4];
            #pragma unroll
            for (int kk = 0; kk < 4; ++kk) {
                float4 v = *(const float4*)&ws[k + kk][tx * 4];
                wr[kk][0] = v.x; wr[kk][1] = v.y; wr[kk][2] = v.z; wr[kk][3] = v.w;
            }
            #pragma unroll
            for (int kk = 0; kk < 4; ++kk)
                #pragma unroll
                for (int r = 0; r < 4; ++r)
                    #pragma unroll
                    for (int c = 0; c < 4; ++c)
                        acc[r][c] = fmaf(xr[r][kk], wr[kk][c], acc[r][c]);
        }
    }

    if (FUSE_ALPHA) {
        const int hh = tx >> 2;
        const int cb = (tx & 3) * 4;
        float asv[4], adv[4];
        #pragma unroll
        for (int c = 0; c < 4; ++c) {
            asv[c] = a_src[hh * 16 + cb + c];
            adv[c] = a_dst[hh * 16 + cb + c];
        }
        #pragma unroll
        for (int r = 0; r < 4; ++r) {
            float ps = 0.f, pd = 0.f;
            #pragma unroll
            for (int c = 0; c < 4; ++c) {
                ps = fmaf(acc[r][c], asv[c], ps);
                pd = fmaf(acc[r][c], adv[c], pd);
            }
            ps += __shfl_xor(ps, 1); ps += __shfl_xor(ps, 2);
            pd += __shfl_xor(pd, 1); pd += __shfl_xor(pd, 2);
            int g = rowBase + ty * 4 + r;
            if (g < n) {
                float4 v = make_float4(acc[r][0], acc[r][1], acc[r][2], acc[r][3]);
                *(float4*)&h[(size_t)g * 64 + tx * 4] = v;
                if ((tx & 3) == 0) {
                    as_[g * 4 + hh] = ps;
                    ad_[g * 4 + hh] = pd;
                }
            }
        }
    } else {
        #pragma unroll
        for (int r = 0; r < 4; ++r) {
            int g = rowBase + ty * 4 + r;
            if (g < n && tx * 4 < HC) {
                float4 v = make_float4(acc[r][0], acc[r][1], acc[r][2], acc[r][3]);
                *(float4*)&h[(size_t)g * HC + tx * 4] = v;
            }
        }
    }
}

// as[n,h] = sum_c h[n,h,c]*a_src[h,c]; one thread per (n,h) — layer 3 only
__global__ void alpha_kernel(const float* __restrict__ h, const float* __restrict__ a_src,
                             const float* __restrict__ a_dst, float* __restrict__ as_,
                             float* __restrict__ ad_, int n, int H, int C) {
    int idx = blockIdx.x * blockDim.x + threadIdx.x;
    if (idx >= n * H) return;
    int hh = idx % H;
    const float* hr = h + (size_t)(idx / H) * H * C + hh * C;
    float s = 0.f, d = 0.f;
    for (int c = 0; c < C; ++c) {
        float v = hr[c];
        s = fmaf(v, a_src[hh * C + c], s);
        d = fmaf(v, a_dst[hh * C + c], d);
    }
    as_[idx] = s;
    ad_[idx] = d;
}

// ---------------- aggregation: single-pass online softmax + gather ----------
// One wave per destination node. Per 64-edge chunk:
//   phase A (lane = edge): parallel col/as4 gathers, per-head leaky+online
//     max/sum via shfl_xor tree, weights -> wave-private LDS.
//   phase B (lane = channel): h-row gathers, unrolled x4 for MLP.
template <int H, int C, bool RELU>
__global__ __launch_bounds__(256) void aggr_kernel(
    const float* __restrict__ h, const float* __restrict__ as_,
    const float* __restrict__ ad_, const int* __restrict__ rowptr,
    const int* __restrict__ col, const float* __restrict__ b,
    float* __restrict__ out, int n) {
    constexpr int HC = H * C;
    __shared__ float wls[4][64][H];
    __shared__ int   sls[4][64];
    const int wib  = threadIdx.x >> 6;
    const int lane = threadIdx.x & 63;
    const int wid  = blockIdx.x * 4 + wib;
    if (wid >= n) return;

    const int p0 = rowptr[wid], p1 = rowptr[wid + 1];
    const int deg = p1 - p0;

    float adv[H];
    #pragma unroll
    for (int hh = 0; hh < H; ++hh) adv[hh] = ad_[wid * H + hh];

    const int myh = (HC < 64 && lane >= HC) ? 0 : lane / C;

    float m[H], sum[H];
    #pragma unroll
    for (int hh = 0; hh < H; ++hh) { m[hh] = -3.4e38f; sum[hh] = 0.f; }
    float acc = 0.f;

    for (int ch = 0; ch * 64 < deg; ++ch) {
        const int idx = p0 + ch * 64 + lane;
        const bool valid = idx < p1;
        int s = 0;
        float e[H];
        if (valid) {
            s = col[idx];
            if (H == 4) {
                float4 a4 = *(const float4*)&as_[s * 4];
                e[0] = a4.x + adv[0]; e[1] = a4.y + adv[1];
                e[2] = a4.z + adv[2]; e[3] = a4.w + adv[3];
            } else {
                e[0] = as_[s] + adv[0];
            }
            #pragma unroll
            for (int hh = 0; hh < H; ++hh)
                e[hh] = (e[hh] >= 0.f) ? e[hh] : NEG_SLOPE * e[hh];
        } else {
            #pragma unroll
            for (int hh = 0; hh < H; ++hh) e[hh] = -3.4e38f;
        }
        // per-head chunk max (wave-wide)
        float f[H], w[H];
        #pragma unroll
        for (int hh = 0; hh < H; ++hh) {
            float v = e[hh];
            #pragma unroll
            for (int d = 1; d < 64; d <<= 1) v = fmaxf(v, __shfl_xor(v, d));
            float mn = fmaxf(m[hh], v);
            f[hh] = expf(m[hh] - mn);     // rescale for previous chunks (0 on first)
            m[hh] = mn;
            w[hh] = expf(e[hh] - mn);     // 0 for invalid lanes
        }
        // per-head chunk sum
        #pragma unroll
        for (int hh = 0; hh < H; ++hh) {
            float v = w[hh];
            #pragma unroll
            for (int d = 1; d < 64; d <<= 1) v += __shfl_xor(v, d);
            sum[hh] = sum[hh] * f[hh] + v;
        }
        // publish weights to wave-private LDS
        #pragma unroll
        for (int hh = 0; hh < H; ++hh) wls[wib][lane][hh] = w[hh];
        sls[wib][lane] = s;
        __builtin_amdgcn_wave_barrier();

        // rescale accumulator (f is wave-uniform per head)
        float fmy;
        if (H == 1) fmy = f[0];
        else {
            float a = (myh & 1) ? f[1] : f[0];
            float c2 = (myh & 1) ? f[3] : f[2];
            fmy = (myh & 2) ? c2 : a;
        }
        acc *= fmy;

        const int cnt = min(64, deg - ch * 64);
        int p = 0;
        for (; p + 4 <= cnt; p += 4) {
            int s0 = sls[wib][p],     s1 = sls[wib][p + 1];
            int s2 = sls[wib][p + 2], s3 = sls[wib][p + 3];
            float w0 = wls[wib][p][myh],     w1 = wls[wib][p + 1][myh];
            float w2 = wls[wib][p + 2][myh], w3 = wls[wib][p + 3][myh];
            float h0 = 0.f, h1 = 0.f, h2 = 0.f, h3 = 0.f;
            if (lane < HC) {
                h0 = h[(size_t)s0 * HC + lane];
                h1 = h[(size_t)s1 * HC + lane];
                h2 = h[(size_t)s2 * HC + lane];
                h3 = h[(size_t)s3 * HC + lane];
            }
            acc = fmaf(w0, h0, acc);
            acc = fmaf(w1, h1, acc);
            acc = fmaf(w2, h2, acc);
            acc = fmaf(w3, h3, acc);
        }
        for (; p < cnt; ++p) {
            int ss = sls[wib][p];
            float ww = wls[wib][p][myh];
            float hv = (lane < HC) ? h[(size_t)ss * HC + lane] : 0.f;
            acc = fmaf(ww, hv, acc);
        }
        __builtin_amdgcn_wave_barrier();  // before next chunk overwrites LDS
    }

    if (lane < HC) {
        float smy;
        if (H == 1) smy = sum[0];
        else {
            float a = (myh & 1) ? sum[1] : sum[0];
            float c2 = (myh & 1) ? sum[3] : sum[2];
            smy = (myh & 2) ? c2 : a;
        }
        float r = acc / (smy + 1e-16f) + b[lane];
        out[(size_t)wid * HC + lane] = RELU ? fmaxf(r, 0.f) : r;
    }
}

// ---------------- launch ----------------

extern "C" void kernel_launch(void* const* d_in, const int* in_sizes, int n_in,
                              void* d_out, int out_size, void* d_ws, size_t ws_size,
                              hipStream_t stream) {
    const float* x      = (const float*)d_in[0];
    const int*   ei     = (const int*)d_in[1];
    const float* W1     = (const float*)d_in[2];
    const float* a_src1 = (const float*)d_in[3];
    const float* a_dst1 = (const float*)d_in[4];
    const float* b1     = (const float*)d_in[5];
    const float* W2     = (const float*)d_in[6];
    const float* a_src2 = (const float*)d_in[7];
    const float* a_dst2 = (const float*)d_in[8];
    const float* b2     = (const float*)d_in[9];
    const float* W3     = (const float*)d_in[10];
    const float* a_src3 = (const float*)d_in[11];
    const float* a_dst3 = (const float*)d_in[12];
    const float* b3     = (const float*)d_in[13];
    float* out = (float*)d_out;

    const int NFEAT = 256, NHID = 64;
    const int N = in_sizes[0] / NFEAT;   // 50000
    const int E = in_sizes[1] / 2;       // 800000
    const int M = E + N;                 // edges incl. self-loops

    char* p = (char*)d_ws;
    auto alloc = [&](size_t bytes) {
        char* r = p;
        p += (bytes + 255) & ~(size_t)255;
        return r;
    };
    int*   hist   = (int*)alloc((size_t)N * 4);
    int*   rowptr = (int*)alloc((size_t)(N + 1) * 4);
    int*   fill   = (int*)alloc((size_t)N * 4);
    int*   col    = (int*)alloc((size_t)M * 4);
    float* hbuf   = (float*)alloc((size_t)N * NHID * 4);
    float* xbuf   = (float*)alloc((size_t)N * NHID * 4);
    float* asb    = (float*)alloc((size_t)N * 4 * 4);
    float* adb    = (float*)alloc((size_t)N * 4 * 4);

    dim3 blk(256);
    const int gemmGrid = (N + 63) / 64;
    const int aggrGrid = (N + 3) / 4;

    // CSR build (shared across all layers)
    init_hist<<<(N + 255) / 256, blk, 0, stream>>>(hist, N);
    edge_hist<<<(E + 255) / 256, blk, 0, stream>>>(ei, hist, E);
    scan_kernel<<<1, 1024, 0, stream>>>(hist, rowptr, fill, N);
    scatter_kernel<<<(M + 255) / 256, blk, 0, stream>>>(ei, fill, col, E, N);

    // layer 1: 256 -> 4x16, relu  (alpha fused into gemm)
    gemm_tiled<256, 64, true><<<gemmGrid, blk, 0, stream>>>(
        x, W1, a_src1, a_dst1, hbuf, asb, adb, N);
    aggr_kernel<4, 16, true><<<aggrGrid, blk, 0, stream>>>(
        hbuf, asb, adb, rowptr, col, b1, xbuf, N);

    // layer 2: 64 -> 4x16, relu
    gemm_tiled<64, 64, true><<<gemmGrid, blk, 0, stream>>>(
        xbuf, W2, a_src2, a_dst2, hbuf, asb, adb, N);
    aggr_kernel<4, 16, true><<<aggrGrid, blk, 0, stream>>>(
        hbuf, asb, adb, rowptr, col, b2, xbuf, N);

    // layer 3: 64 -> 1x40, no relu
    gemm_tiled<64, 40, false><<<gemmGrid, blk, 0, stream>>>(
        xbuf, W3, nullptr, nullptr, hbuf, nullptr, nullptr, N);
    alpha_kernel<<<(N + 255) / 256, blk, 0, stream>>>(hbuf, a_src3, a_dst3, asb, adb, N, 1, 40);
    aggr_kernel<1, 40, false><<<aggrGrid, blk, 0, stream>>>(
        hbuf, asb, adb, rowptr, col, b3, out, N);
}